// Round 2
// baseline (475.767 us; speedup 1.0000x reference)
//
#include <hip/hip_runtime.h>
#include <math.h>

// ---------------------------------------------------------------------------
// SGCN forward — CSR pull aggregation fused with dense layers.
//
// R6 change: fill_k was write-amplification-bound (WRITE_SIZE 134MB for a
// 10MB col array; 8x re-stream of the edge list for reads). Replaced
// hist_k+fill_k with a 2-pass bucket sort:
//   * bucket_k: block-local LDS count -> one global atomicAdd per partition
//     per block -> dense append of 4B packed records (src:17b | localdst:15b)
//     into 8 per-partition buffers. deg histogram fused in (saves hist pass).
//   * scatter_k: per-partition (XCD-affine) blocks stream their 1.3MB record
//     buffer and scatter into their 2.5MB col region; per-XCD working set
//     ~3.8MB fits L2 -> ~1 writeback per col line.
// Staging buffer aliases zh/xh (dead after scatter_k; stream-ordered).
// Layers (fp16 dot2 datapath, R5) unchanged.
// ---------------------------------------------------------------------------

typedef _Float16 h2 __attribute__((ext_vector_type(2)));
typedef _Float16 h4 __attribute__((ext_vector_type(4)));

__device__ inline float fdot2f(h2 a, h2 b, float c) {
#if __has_builtin(__builtin_amdgcn_fdot2)
    return __builtin_amdgcn_fdot2(a, b, c, false);
#else
    return fmaf((float)a.x, (float)b.x, fmaf((float)a.y, (float)b.y, c));
#endif
}

__device__ inline h4 shflx4(h4 v, int m) {
    int2 i = __builtin_bit_cast(int2, v);
    i.x = __shfl_xor(i.x, m);
    i.y = __shfl_xor(i.y, m);
    return __builtin_bit_cast(h4, i);
}

__device__ inline float fast_tanh(float v) {
    float e = __expf(2.0f * v);
    return 1.0f - 2.0f / (e + 1.0f);
}

// ------------------------------- CSR build ---------------------------------
// Pass A: fused histogram + partition bucketing. Each block handles 2048
// contiguous edges; per-partition LDS count; one global reserve per
// partition per block; dense 4B-record appends.

__global__ void __launch_bounds__(256) bucket_k(
    const int* __restrict__ pos, const int* __restrict__ neg,
    int* __restrict__ deg, int* __restrict__ pcnt,
    unsigned* __restrict__ ebuf, int E, int n, int cap)
{
    __shared__ int cnt[8], gbase[8], lcnt[8];
    const int K = 8;
    int tid = threadIdx.x;
    int base = blockIdx.x * (256 * K);
    int n2 = 2 * n;
    int node[K], src[K], part[K];

    if (tid < 8) cnt[tid] = 0;
    __syncthreads();

    #pragma unroll
    for (int k = 0; k < K; ++k) {
        int e = base + k * 256 + tid;
        if (e < 2 * E) {
            int nd, sr;
            if (e < E) { nd = pos[E + e];            sr = pos[e]; }
            else       { int ee = e - E; nd = n + neg[E + ee]; sr = neg[ee]; }
            node[k] = nd; src[k] = sr;
            int p = (int)(((long long)nd * 8) / n2);
            part[k] = p;
            atomicAdd(&deg[nd], 1);
            atomicAdd(&cnt[p], 1);
        } else part[k] = -1;
    }
    __syncthreads();
    if (tid < 8) {
        gbase[tid] = atomicAdd(&pcnt[tid], cnt[tid]);
        lcnt[tid] = 0;
    }
    __syncthreads();
    #pragma unroll
    for (int k = 0; k < K; ++k) {
        int p = part[k];
        if (p >= 0) {
            int r = gbase[p] + atomicAdd(&lcnt[p], 1);
            int lo = (int)(((long long)n2 * p) >> 3);
            if (r < cap)
                ebuf[(size_t)p * cap + r] =
                    ((unsigned)(node[k] - lo) << 17) | (unsigned)src[k];
        }
    }
}

__global__ void __launch_bounds__(256) scan1_k(
    const int* __restrict__ deg, int* __restrict__ cur,
    int* __restrict__ bsum, int n2)
{
    __shared__ int s[256];
    int tid = threadIdx.x;
    int i = blockIdx.x * 256 + tid;
    int v = (i < n2) ? deg[i] : 0;
    s[tid] = v;
    __syncthreads();
    for (int off = 1; off < 256; off <<= 1) {
        int t = (tid >= off) ? s[tid - off] : 0;
        __syncthreads();
        s[tid] += t;
        __syncthreads();
    }
    if (i < n2) cur[i] = s[tid] - v;
    if (tid == 255) bsum[blockIdx.x] = s[255];
}

__global__ void __launch_bounds__(1024) scan2_k(int* __restrict__ bsum, int nb)
{
    __shared__ int s[1024];
    int tid = threadIdx.x;
    int v = (tid < nb) ? bsum[tid] : 0;
    s[tid] = v;
    __syncthreads();
    for (int off = 1; off < 1024; off <<= 1) {
        int t = (tid >= off) ? s[tid - off] : 0;
        __syncthreads();
        s[tid] += t;
        __syncthreads();
    }
    if (tid < nb) bsum[tid] = s[tid] - v;
}

__global__ void __launch_bounds__(256) scan3_k(
    int* __restrict__ cur, const int* __restrict__ bsum, int n2)
{
    int i = blockIdx.x * 256 + threadIdx.x;
    if (i < n2) cur[i] += bsum[blockIdx.x];
}

// Pass B: per-partition scatter. Block serves partition (blockIdx & 7) so the
// dirty col region per XCD is ~2.5MB (L2-resident) under round-robin dispatch.
__global__ void __launch_bounds__(256) scatter_k(
    const unsigned* __restrict__ ebuf, const int* __restrict__ pcnt,
    int* __restrict__ cur, int* __restrict__ col, int n, int cap,
    int blocksPerPart)
{
    int p = blockIdx.x & 7;
    int wb = blockIdx.x >> 3;
    int n2 = 2 * n;
    int lo = (int)(((long long)n2 * p) >> 3);
    int cnt = min(pcnt[p], cap);
    const unsigned* buf = ebuf + (size_t)p * cap;
    int stride = blocksPerPart * 256;
    for (int i = wb * 256 + (int)threadIdx.x; i < cnt; i += stride) {
        unsigned v = buf[i];
        int src = (int)(v & 0x1FFFFu);
        int nd = lo + (int)(v >> 17);
        int slot = atomicAdd(&cur[nd], 1);
        col[slot] = src;
    }
}

// ------------------------------ x -> fp16 ----------------------------------

__global__ void __launch_bounds__(256) cvt_k(
    const float4* __restrict__ x, h4* __restrict__ xh, int n4)
{
    int i = blockIdx.x * 256 + threadIdx.x;
    if (i < n4) {
        float4 v = x[i];
        h4 o = { (_Float16)v.x, (_Float16)v.y, (_Float16)v.z, (_Float16)v.w };
        xh[i] = o;
    }
}

// ------------------------- fused pull + dense layers ------------------------
// One wave per node (grid-stride over nodes). Gather: lane = 16g+f, group g
// handles edge p0+4*it+g, f indexes an h4 (4 halves) of the 64-h row.
// Dense: lane c computes output column c (c<32 pos path, c>=32 neg path)
// with v_dot2_f32_f16 against packed-h4 weights in LDS.

__global__ void __launch_bounds__(256, 8) layer1_pull(
    const h4* __restrict__ xh,
    const int* __restrict__ cur, const int* __restrict__ col,
    const float* __restrict__ W1p, const float* __restrict__ b1p,
    const float* __restrict__ W1n, const float* __restrict__ b1n,
    _Float16* __restrict__ zh, int n)
{
    // Wq[j4*64 + c] = rows 4j4..4j4+3 (of the 128-row [a|x] matrix), column c
    // (c<32 -> W1p col c, else W1n col c-32).
    __shared__ h4 Wq[32 * 64];            // 16 KB
    __shared__ h4 vec4s[4][48];           // per-wave: a(16) | b(16) | xi(16)
    int tid = threadIdx.x;
    for (int idx = tid; idx < 32 * 64; idx += 256) {
        int j4 = idx >> 6, c = idx & 63, cw = c & 31;
        const float* Ws = (c < 32) ? W1p : W1n;
        int r = 4 * j4;
        Wq[idx] = h4{ (_Float16)Ws[r * 32 + cw],       (_Float16)Ws[(r + 1) * 32 + cw],
                      (_Float16)Ws[(r + 2) * 32 + cw], (_Float16)Ws[(r + 3) * 32 + cw] };
    }
    __syncthreads();

    int wave = tid >> 6, lane = tid & 63;
    int g = lane >> 4, f = lane & 15;
    int c = lane;
    float bb = (c < 32) ? b1p[c] : b1n[c - 32];
    int ab4 = (c < 32) ? 0 : 16;
    h4* vec = vec4s[wave];

    int stride = gridDim.x * 4;
    for (int node = blockIdx.x * 4 + wave; node < n; node += stride) {
        int p0 = node ? cur[node - 1] : 0;
        int p1 = cur[node];
        int q0 = cur[n + node - 1];
        int q1 = cur[n + node];

        h4 a = {}, b = {};
        #pragma unroll 2
        for (int it = p0 + g; it < p1; it += 4) {
            h4 t = xh[(unsigned)(col[it] * 16 + f)];
            a = a + t;
        }
        #pragma unroll 2
        for (int it = q0 + g; it < q1; it += 4) {
            h4 t = xh[(unsigned)(col[it] * 16 + f)];
            b = b + t;
        }
        a = a + shflx4(a, 16); a = a + shflx4(a, 32);
        b = b + shflx4(b, 16); b = b + shflx4(b, 32);
        _Float16 rp = (_Float16)(1.0f / (float)max(p1 - p0, 1));
        _Float16 rq = (_Float16)(1.0f / (float)max(q1 - q0, 1));
        h4 rpv = { rp, rp, rp, rp }, rqv = { rq, rq, rq, rq };
        a = a * rpv;
        b = b * rqv;
        h4 xi = xh[(unsigned)(node * 16 + f)];
        h4 sv = (g == 0) ? a : (g == 1) ? b : xi;
        if (g < 3) vec[g * 16 + f] = sv;
        __builtin_amdgcn_wave_barrier();

        float acc = bb;
        #pragma unroll
        for (int j4 = 0; j4 < 16; ++j4) {            // a-part (ap or an by half)
            h4 v = vec[ab4 + j4];
            h4 w = Wq[j4 * 64 + c];
            h2 vl = { v.x, v.y }, vh = { v.z, v.w };
            h2 wl = { w.x, w.y }, wh = { w.z, w.w };
            acc = fdot2f(vl, wl, acc);
            acc = fdot2f(vh, wh, acc);
        }
        #pragma unroll
        for (int j4 = 0; j4 < 16; ++j4) {            // x-part (shared)
            h4 v = vec[32 + j4];
            h4 w = Wq[(16 + j4) * 64 + c];
            h2 vl = { v.x, v.y }, vh = { v.z, v.w };
            h2 wl = { w.x, w.y }, wh = { w.z, w.w };
            acc = fdot2f(vl, wl, acc);
            acc = fdot2f(vh, wh, acc);
        }
        zh[(unsigned)(node * 64 + c)] = (_Float16)fast_tanh(acc);
        __builtin_amdgcn_wave_barrier();
    }
}

__global__ void __launch_bounds__(256, 8) layer2_pull(
    const h4* __restrict__ zh4,
    const int* __restrict__ cur, const int* __restrict__ col,
    const float* __restrict__ W2p, const float* __restrict__ b2p,
    const float* __restrict__ W2n, const float* __restrict__ b2n,
    float* __restrict__ out, int n)
{
    // Wq[j4*64 + c] = rows 4j4..4j4+3 of the 96-row [seg1|seg2|z] matrix.
    __shared__ h4 Wq[24 * 64];            // 12 KB
    __shared__ h4 vec4s[4][48];           // per-wave: Ap(16) | An(16) | z(16)
    int tid = threadIdx.x;
    for (int idx = tid; idx < 24 * 64; idx += 256) {
        int j4 = idx >> 6, c = idx & 63, cw = c & 31;
        const float* Ws = (c < 32) ? W2p : W2n;
        int r = 4 * j4;
        Wq[idx] = h4{ (_Float16)Ws[r * 32 + cw],       (_Float16)Ws[(r + 1) * 32 + cw],
                      (_Float16)Ws[(r + 2) * 32 + cw], (_Float16)Ws[(r + 3) * 32 + cw] };
    }
    __syncthreads();

    int wave = tid >> 6, lane = tid & 63;
    int g = lane >> 4, f = lane & 15;
    int c = lane;
    float bb = (c < 32) ? b2p[c] : b2n[c - 32];
    // vec segments (h4 units): pos half: Ap[0:32]=0..7, An[32:64]=24..31,
    // z[0:32]=32..39 ; neg half: Ap[32:64]=8..15, An[0:32]=16..23, z[32:64]=40..47
    int s1 = (c < 32) ? 0 : 8;
    int s2 = (c < 32) ? 24 : 16;
    int s3 = (c < 32) ? 32 : 40;
    h4* vec = vec4s[wave];

    int stride = gridDim.x * 4;
    for (int node = blockIdx.x * 4 + wave; node < n; node += stride) {
        int p0 = node ? cur[node - 1] : 0;
        int p1 = cur[node];
        int q0 = cur[n + node - 1];
        int q1 = cur[n + node];

        h4 a = {}, b = {};
        #pragma unroll 2
        for (int it = p0 + g; it < p1; it += 4) {
            h4 t = zh4[(unsigned)(col[it] * 16 + f)];
            a = a + t;
        }
        #pragma unroll 2
        for (int it = q0 + g; it < q1; it += 4) {
            h4 t = zh4[(unsigned)(col[it] * 16 + f)];
            b = b + t;
        }
        a = a + shflx4(a, 16); a = a + shflx4(a, 32);
        b = b + shflx4(b, 16); b = b + shflx4(b, 32);
        _Float16 rp = (_Float16)(1.0f / (float)max(p1 - p0, 1));
        _Float16 rq = (_Float16)(1.0f / (float)max(q1 - q0, 1));
        h4 rpv = { rp, rp, rp, rp }, rqv = { rq, rq, rq, rq };
        a = a * rpv;
        b = b * rqv;
        h4 zi = zh4[(unsigned)(node * 16 + f)];
        h4 sv = (g == 0) ? a : (g == 1) ? b : zi;
        if (g < 3) vec[g * 16 + f] = sv;
        __builtin_amdgcn_wave_barrier();

        float acc = bb;
        #pragma unroll
        for (int j4 = 0; j4 < 8; ++j4) {             // segment 1
            h4 v = vec[s1 + j4];
            h4 w = Wq[j4 * 64 + c];
            h2 vl = { v.x, v.y }, vh = { v.z, v.w };
            h2 wl = { w.x, w.y }, wh = { w.z, w.w };
            acc = fdot2f(vl, wl, acc);
            acc = fdot2f(vh, wh, acc);
        }
        #pragma unroll
        for (int j4 = 0; j4 < 8; ++j4) {             // segment 2
            h4 v = vec[s2 + j4];
            h4 w = Wq[(8 + j4) * 64 + c];
            h2 vl = { v.x, v.y }, vh = { v.z, v.w };
            h2 wl = { w.x, w.y }, wh = { w.z, w.w };
            acc = fdot2f(vl, wl, acc);
            acc = fdot2f(vh, wh, acc);
        }
        #pragma unroll
        for (int j4 = 0; j4 < 8; ++j4) {             // z segment
            h4 v = vec[s3 + j4];
            h4 w = Wq[(16 + j4) * 64 + c];
            h2 vl = { v.x, v.y }, vh = { v.z, v.w };
            h2 wl = { w.x, w.y }, wh = { w.z, w.w };
            acc = fdot2f(vl, wl, acc);
            acc = fdot2f(vh, wh, acc);
        }
        out[(size_t)node * 64 + c] = fast_tanh(acc);
        __builtin_amdgcn_wave_barrier();
    }
}

extern "C" void kernel_launch(void* const* d_in, const int* in_sizes, int n_in,
                              void* d_out, int out_size, void* d_ws, size_t ws_size,
                              hipStream_t stream)
{
    const float* x   = (const float*)d_in[0];
    const float* W1p = (const float*)d_in[1];
    const float* b1p = (const float*)d_in[2];
    const float* W1n = (const float*)d_in[3];
    const float* b1n = (const float*)d_in[4];
    const float* W2p = (const float*)d_in[5];
    const float* b2p = (const float*)d_in[6];
    const float* W2n = (const float*)d_in[7];
    const float* b2n = (const float*)d_in[8];
    const int*   pos = (const int*)d_in[9];
    const int*   neg = (const int*)d_in[10];

    int n = in_sizes[0] / 64;       // 100000
    int E = in_sizes[9] / 2;        // 1250000
    int n2 = 2 * n;
    int cap = (2 * E) / 8 + 16384;  // per-partition record capacity (~31 sigma slack)

    // workspace: deg[2n] | pcnt[8] | cur[2n] | bsum[1024] | col[2E] |
    //            union{ ebuf[8*cap u32] (dead after scatter) , zh | xh (fp16) }
    int*      deg  = (int*)d_ws;
    int*      pcnt = deg + n2;
    int*      cur  = pcnt + 8;
    int*      bsum = cur + n2;
    int*      col  = bsum + 1024;
    unsigned* ebuf = (unsigned*)(col + 2 * (size_t)E);
    _Float16* zh   = (_Float16*)ebuf;            // aliases ebuf (stream-ordered)
    _Float16* xh   = zh + (size_t)n * 64;        // beyond ebuf's 8*cap*4B extent

    hipMemsetAsync(deg, 0, (size_t)(n2 + 8) * sizeof(int), stream);

    int bblocks = (2 * E + 2047) / 2048;
    int sblocks = (n2 + 255) / 256;

    bucket_k<<<bblocks, 256, 0, stream>>>(pos, neg, deg, pcnt, ebuf, E, n, cap);
    scan1_k <<<sblocks, 256, 0, stream>>>(deg, cur, bsum, n2);
    scan2_k <<<1, 1024, 0, stream>>>(bsum, sblocks);
    scan3_k <<<sblocks, 256, 0, stream>>>(cur, bsum, n2);

    int bpp = 128;                           // blocks per dst-partition
    scatter_k<<<8 * bpp, 256, 0, stream>>>(ebuf, pcnt, cur, col, n, cap, bpp);

    int n4 = n * 16;                         // h4 elements of x
    cvt_k  <<<(n4 + 255) / 256, 256, 0, stream>>>((const float4*)x, (h4*)xh, n4);

    int lblocks = 2048;   // 8 blocks/CU resident; grid-stride over nodes
    layer1_pull<<<lblocks, 256, 0, stream>>>((const h4*)xh, cur, col,
                                             W1p, b1p, W1n, b1n, zh, n);
    layer2_pull<<<lblocks, 256, 0, stream>>>((const h4*)zh, cur, col,
                                             W2p, b2p, W2n, b2n,
                                             (float*)d_out, n);
}

// Round 3
// 286.731 us; speedup vs baseline: 1.6593x; 1.6593x over previous
//
#include <hip/hip_runtime.h>
#include <math.h>

// ---------------------------------------------------------------------------
// SGCN forward — CSR pull aggregation fused with dense layers.
//
// R7 change: R6's bucket_k/scatter_k were bound by per-edge GLOBAL atomics
// (2.5M atomicAdd each -> ~80MB of 32B-sector EA writes per kernel; both
// kernels ~105us at <3% VALUBusy). New build has ZERO per-edge global atomics:
//   * bucket_k: 391 buckets of 512 dst nodes (p = nd>>9); LDS per-bucket
//     count; ONE global atomicAdd per bucket per block (~240K total); dense
//     4B record appends ((nd&511)<<17 | src). deg histogram eliminated.
//   * bscan_k: 1-block scan of 391 bucket totals -> global bases (replaces
//     scan1/2/3; per-node prefix moves into scatter_k's LDS scan).
//   * scatter_k: 1 block per bucket; LDS histogram over 512 local nodes ->
//     LDS scan -> dense cur[] write (inclusive prefix); records placed into
//     LDS lcol[8192] via LDS atomics; segment streamed to col[] contiguously
//     (write amp ~1).
// Layers (fp16 v_dot2 datapath, R5) unchanged.
// ---------------------------------------------------------------------------

typedef _Float16 h2 __attribute__((ext_vector_type(2)));
typedef _Float16 h4 __attribute__((ext_vector_type(4)));

__device__ inline float fdot2f(h2 a, h2 b, float c) {
#if __has_builtin(__builtin_amdgcn_fdot2)
    return __builtin_amdgcn_fdot2(a, b, c, false);
#else
    return fmaf((float)a.x, (float)b.x, fmaf((float)a.y, (float)b.y, c));
#endif
}

__device__ inline h4 shflx4(h4 v, int m) {
    int2 i = __builtin_bit_cast(int2, v);
    i.x = __shfl_xor(i.x, m);
    i.y = __shfl_xor(i.y, m);
    return __builtin_bit_cast(h4, i);
}

__device__ inline float fast_tanh(float v) {
    float e = __expf(2.0f * v);
    return 1.0f - 2.0f / (e + 1.0f);
}

// ------------------------------- CSR build ---------------------------------
// Bucket = 512 consecutive flattened dst ids (2n space: pos then neg).
// Record = (nd & 511) << 17 | src   (src < 2^17, rel < 2^9 -> 26 bits).

#define BSHIFT 9
#define BSIZE  512
#define NBMAX  512
#define CAP    8192   // per-bucket record capacity; mean 6400, +22 sigma

__global__ void __launch_bounds__(256) bucket_k(
    const int* __restrict__ pos, const int* __restrict__ neg,
    int* __restrict__ pcnt, unsigned* __restrict__ ebuf,
    int E, int n, int nb)
{
    __shared__ int cnt[NBMAX], gbase[NBMAX], lcnt[NBMAX];
    const int K = 16;
    int tid = threadIdx.x;
    int base = blockIdx.x * (256 * K);

    for (int i = tid; i < nb; i += 256) cnt[i] = 0;
    __syncthreads();

    unsigned val[K];
    int part[K];
    #pragma unroll
    for (int k = 0; k < K; ++k) {
        int e = base + k * 256 + tid;
        part[k] = -1;
        if (e < 2 * E) {
            int nd, sr;
            if (e < E) { nd = pos[E + e];                 sr = pos[e]; }
            else       { int ee = e - E; nd = n + neg[E + ee]; sr = neg[ee]; }
            int p = nd >> BSHIFT;
            part[k] = p;
            val[k] = ((unsigned)(nd & (BSIZE - 1)) << 17) | (unsigned)sr;
            atomicAdd(&cnt[p], 1);
        }
    }
    __syncthreads();
    for (int i = tid; i < nb; i += 256) {
        int c = cnt[i];
        gbase[i] = c ? atomicAdd(&pcnt[i], c) : 0;
        lcnt[i] = 0;
    }
    __syncthreads();
    #pragma unroll
    for (int k = 0; k < K; ++k) {
        int p = part[k];
        if (p >= 0) {
            int off = gbase[p] + atomicAdd(&lcnt[p], 1);
            if (off < CAP) ebuf[(size_t)p * CAP + off] = val[k];
        }
    }
}

__global__ void __launch_bounds__(512) bscan_k(
    const int* __restrict__ pcnt, int* __restrict__ bbase, int nb)
{
    __shared__ int s[512];
    int tid = threadIdx.x;
    int v = (tid < nb) ? pcnt[tid] : 0;
    s[tid] = v;
    __syncthreads();
    for (int off = 1; off < 512; off <<= 1) {
        int t = (tid >= off) ? s[tid - off] : 0;
        __syncthreads();
        s[tid] += t;
        __syncthreads();
    }
    if (tid < nb) bbase[tid] = s[tid] - v;   // exclusive base
}

// One block per bucket. LDS histogram -> scan -> dense cur write -> LDS
// staging of col segment -> contiguous global stream-out.
__global__ void __launch_bounds__(256) scatter_k(
    const unsigned* __restrict__ ebuf, const int* __restrict__ pcnt,
    const int* __restrict__ bbase,
    int* __restrict__ cur, int* __restrict__ col, int n)
{
    __shared__ int lcnt[BSIZE], lbase[BSIZE], sc[256];
    __shared__ int lcol[CAP];
    int p = blockIdx.x;
    int tid = threadIdx.x;
    int n2 = 2 * n;
    int lo = p << BSHIFT;
    int nn = min(BSIZE, n2 - lo);
    int cnt = min(pcnt[p], CAP);
    const unsigned* buf = ebuf + (size_t)p * CAP;

    lcnt[tid] = 0; lcnt[tid + 256] = 0;
    __syncthreads();
    for (int i = tid; i < cnt; i += 256) {
        unsigned v = buf[i];
        atomicAdd(&lcnt[v >> 17], 1);
    }
    __syncthreads();
    int a0 = lcnt[2 * tid], a1 = lcnt[2 * tid + 1];
    int s = a0 + a1;
    sc[tid] = s;
    __syncthreads();
    for (int off = 1; off < 256; off <<= 1) {
        int t = (tid >= off) ? sc[tid - off] : 0;
        __syncthreads();
        sc[tid] += t;
        __syncthreads();
    }
    int excl = sc[tid] - s;
    lbase[2 * tid] = excl;
    lbase[2 * tid + 1] = excl + a0;
    __syncthreads();
    int gb = bbase[p];
    for (int i = tid; i < nn; i += 256)            // inclusive prefix -> cur
        cur[lo + i] = gb + lbase[i] + lcnt[i];
    __syncthreads();
    for (int i = tid; i < cnt; i += 256) {         // place into LDS staging
        unsigned v = buf[i];
        int rel = (int)(v >> 17);
        int slot = atomicAdd(&lbase[rel], 1);
        lcol[slot] = (int)(v & 0x1FFFFu);
    }
    __syncthreads();
    for (int t = tid; t < cnt; t += 256)           // dense stream-out
        col[gb + t] = lcol[t];
}

// ------------------------------ x -> fp16 ----------------------------------

__global__ void __launch_bounds__(256) cvt_k(
    const float4* __restrict__ x, h4* __restrict__ xh, int n4)
{
    int i = blockIdx.x * 256 + threadIdx.x;
    if (i < n4) {
        float4 v = x[i];
        h4 o = { (_Float16)v.x, (_Float16)v.y, (_Float16)v.z, (_Float16)v.w };
        xh[i] = o;
    }
}

// ------------------------- fused pull + dense layers ------------------------
// One wave per node (grid-stride over nodes). Gather: lane = 16g+f, group g
// handles edge p0+4*it+g, f indexes an h4 (4 halves) of the 64-h row.
// Dense: lane c computes output column c (c<32 pos path, c>=32 neg path)
// with v_dot2_f32_f16 against packed-h4 weights in LDS.

__global__ void __launch_bounds__(256, 8) layer1_pull(
    const h4* __restrict__ xh,
    const int* __restrict__ cur, const int* __restrict__ col,
    const float* __restrict__ W1p, const float* __restrict__ b1p,
    const float* __restrict__ W1n, const float* __restrict__ b1n,
    _Float16* __restrict__ zh, int n)
{
    // Wq[j4*64 + c] = rows 4j4..4j4+3 (of the 128-row [a|x] matrix), column c
    // (c<32 -> W1p col c, else W1n col c-32).
    __shared__ h4 Wq[32 * 64];            // 16 KB
    __shared__ h4 vec4s[4][48];           // per-wave: a(16) | b(16) | xi(16)
    int tid = threadIdx.x;
    for (int idx = tid; idx < 32 * 64; idx += 256) {
        int j4 = idx >> 6, c = idx & 63, cw = c & 31;
        const float* Ws = (c < 32) ? W1p : W1n;
        int r = 4 * j4;
        Wq[idx] = h4{ (_Float16)Ws[r * 32 + cw],       (_Float16)Ws[(r + 1) * 32 + cw],
                      (_Float16)Ws[(r + 2) * 32 + cw], (_Float16)Ws[(r + 3) * 32 + cw] };
    }
    __syncthreads();

    int wave = tid >> 6, lane = tid & 63;
    int g = lane >> 4, f = lane & 15;
    int c = lane;
    float bb = (c < 32) ? b1p[c] : b1n[c - 32];
    int ab4 = (c < 32) ? 0 : 16;
    h4* vec = vec4s[wave];

    int stride = gridDim.x * 4;
    for (int node = blockIdx.x * 4 + wave; node < n; node += stride) {
        int p0 = node ? cur[node - 1] : 0;
        int p1 = cur[node];
        int q0 = cur[n + node - 1];
        int q1 = cur[n + node];

        h4 a = {}, b = {};
        #pragma unroll 2
        for (int it = p0 + g; it < p1; it += 4) {
            h4 t = xh[(unsigned)(col[it] * 16 + f)];
            a = a + t;
        }
        #pragma unroll 2
        for (int it = q0 + g; it < q1; it += 4) {
            h4 t = xh[(unsigned)(col[it] * 16 + f)];
            b = b + t;
        }
        a = a + shflx4(a, 16); a = a + shflx4(a, 32);
        b = b + shflx4(b, 16); b = b + shflx4(b, 32);
        _Float16 rp = (_Float16)(1.0f / (float)max(p1 - p0, 1));
        _Float16 rq = (_Float16)(1.0f / (float)max(q1 - q0, 1));
        h4 rpv = { rp, rp, rp, rp }, rqv = { rq, rq, rq, rq };
        a = a * rpv;
        b = b * rqv;
        h4 xi = xh[(unsigned)(node * 16 + f)];
        h4 sv = (g == 0) ? a : (g == 1) ? b : xi;
        if (g < 3) vec[g * 16 + f] = sv;
        __builtin_amdgcn_wave_barrier();

        float acc = bb;
        #pragma unroll
        for (int j4 = 0; j4 < 16; ++j4) {            // a-part (ap or an by half)
            h4 v = vec[ab4 + j4];
            h4 w = Wq[j4 * 64 + c];
            h2 vl = { v.x, v.y }, vh = { v.z, v.w };
            h2 wl = { w.x, w.y }, wh = { w.z, w.w };
            acc = fdot2f(vl, wl, acc);
            acc = fdot2f(vh, wh, acc);
        }
        #pragma unroll
        for (int j4 = 0; j4 < 16; ++j4) {            // x-part (shared)
            h4 v = vec[32 + j4];
            h4 w = Wq[(16 + j4) * 64 + c];
            h2 vl = { v.x, v.y }, vh = { v.z, v.w };
            h2 wl = { w.x, w.y }, wh = { w.z, w.w };
            acc = fdot2f(vl, wl, acc);
            acc = fdot2f(vh, wh, acc);
        }
        zh[(unsigned)(node * 64 + c)] = (_Float16)fast_tanh(acc);
        __builtin_amdgcn_wave_barrier();
    }
}

__global__ void __launch_bounds__(256, 8) layer2_pull(
    const h4* __restrict__ zh4,
    const int* __restrict__ cur, const int* __restrict__ col,
    const float* __restrict__ W2p, const float* __restrict__ b2p,
    const float* __restrict__ W2n, const float* __restrict__ b2n,
    float* __restrict__ out, int n)
{
    // Wq[j4*64 + c] = rows 4j4..4j4+3 of the 96-row [seg1|seg2|z] matrix.
    __shared__ h4 Wq[24 * 64];            // 12 KB
    __shared__ h4 vec4s[4][48];           // per-wave: Ap(16) | An(16) | z(16)
    int tid = threadIdx.x;
    for (int idx = tid; idx < 24 * 64; idx += 256) {
        int j4 = idx >> 6, c = idx & 63, cw = c & 31;
        const float* Ws = (c < 32) ? W2p : W2n;
        int r = 4 * j4;
        Wq[idx] = h4{ (_Float16)Ws[r * 32 + cw],       (_Float16)Ws[(r + 1) * 32 + cw],
                      (_Float16)Ws[(r + 2) * 32 + cw], (_Float16)Ws[(r + 3) * 32 + cw] };
    }
    __syncthreads();

    int wave = tid >> 6, lane = tid & 63;
    int g = lane >> 4, f = lane & 15;
    int c = lane;
    float bb = (c < 32) ? b2p[c] : b2n[c - 32];
    // vec segments (h4 units): pos half: Ap[0:32]=0..7, An[32:64]=24..31,
    // z[0:32]=32..39 ; neg half: Ap[32:64]=8..15, An[0:32]=16..23, z[32:64]=40..47
    int s1 = (c < 32) ? 0 : 8;
    int s2 = (c < 32) ? 24 : 16;
    int s3 = (c < 32) ? 32 : 40;
    h4* vec = vec4s[wave];

    int stride = gridDim.x * 4;
    for (int node = blockIdx.x * 4 + wave; node < n; node += stride) {
        int p0 = node ? cur[node - 1] : 0;
        int p1 = cur[node];
        int q0 = cur[n + node - 1];
        int q1 = cur[n + node];

        h4 a = {}, b = {};
        #pragma unroll 2
        for (int it = p0 + g; it < p1; it += 4) {
            h4 t = zh4[(unsigned)(col[it] * 16 + f)];
            a = a + t;
        }
        #pragma unroll 2
        for (int it = q0 + g; it < q1; it += 4) {
            h4 t = zh4[(unsigned)(col[it] * 16 + f)];
            b = b + t;
        }
        a = a + shflx4(a, 16); a = a + shflx4(a, 32);
        b = b + shflx4(b, 16); b = b + shflx4(b, 32);
        _Float16 rp = (_Float16)(1.0f / (float)max(p1 - p0, 1));
        _Float16 rq = (_Float16)(1.0f / (float)max(q1 - q0, 1));
        h4 rpv = { rp, rp, rp, rp }, rqv = { rq, rq, rq, rq };
        a = a * rpv;
        b = b * rqv;
        h4 zi = zh4[(unsigned)(node * 16 + f)];
        h4 sv = (g == 0) ? a : (g == 1) ? b : zi;
        if (g < 3) vec[g * 16 + f] = sv;
        __builtin_amdgcn_wave_barrier();

        float acc = bb;
        #pragma unroll
        for (int j4 = 0; j4 < 8; ++j4) {             // segment 1
            h4 v = vec[s1 + j4];
            h4 w = Wq[j4 * 64 + c];
            h2 vl = { v.x, v.y }, vh = { v.z, v.w };
            h2 wl = { w.x, w.y }, wh = { w.z, w.w };
            acc = fdot2f(vl, wl, acc);
            acc = fdot2f(vh, wh, acc);
        }
        #pragma unroll
        for (int j4 = 0; j4 < 8; ++j4) {             // segment 2
            h4 v = vec[s2 + j4];
            h4 w = Wq[(8 + j4) * 64 + c];
            h2 vl = { v.x, v.y }, vh = { v.z, v.w };
            h2 wl = { w.x, w.y }, wh = { w.z, w.w };
            acc = fdot2f(vl, wl, acc);
            acc = fdot2f(vh, wh, acc);
        }
        #pragma unroll
        for (int j4 = 0; j4 < 8; ++j4) {             // z segment
            h4 v = vec[s3 + j4];
            h4 w = Wq[(16 + j4) * 64 + c];
            h2 vl = { v.x, v.y }, vh = { v.z, v.w };
            h2 wl = { w.x, w.y }, wh = { w.z, w.w };
            acc = fdot2f(vl, wl, acc);
            acc = fdot2f(vh, wh, acc);
        }
        out[(size_t)node * 64 + c] = fast_tanh(acc);
        __builtin_amdgcn_wave_barrier();
    }
}

extern "C" void kernel_launch(void* const* d_in, const int* in_sizes, int n_in,
                              void* d_out, int out_size, void* d_ws, size_t ws_size,
                              hipStream_t stream)
{
    const float* x   = (const float*)d_in[0];
    const float* W1p = (const float*)d_in[1];
    const float* b1p = (const float*)d_in[2];
    const float* W1n = (const float*)d_in[3];
    const float* b1n = (const float*)d_in[4];
    const float* W2p = (const float*)d_in[5];
    const float* b2p = (const float*)d_in[6];
    const float* W2n = (const float*)d_in[7];
    const float* b2n = (const float*)d_in[8];
    const int*   pos = (const int*)d_in[9];
    const int*   neg = (const int*)d_in[10];

    int n = in_sizes[0] / 64;       // 100000
    int E = in_sizes[9] / 2;        // 1250000
    int n2 = 2 * n;
    int nb = (n2 + BSIZE - 1) / BSIZE;   // 391 buckets

    // workspace: pcnt[512] | bbase[512] | cur[2n] | col[2E] |
    //            union{ ebuf[nb*CAP u32] (dead after scatter) , zh | xh (fp16) }
    int*      pcnt  = (int*)d_ws;
    int*      bbase = pcnt + NBMAX;
    int*      cur   = bbase + NBMAX;
    int*      col   = cur + n2;
    unsigned* ebuf  = (unsigned*)(col + 2 * (size_t)E);
    _Float16* zh    = (_Float16*)ebuf;           // aliases ebuf (stream-ordered)
    _Float16* xh    = zh + (size_t)n * 64;       // overlaps ebuf tail; cvt runs after scatter

    hipMemsetAsync(pcnt, 0, NBMAX * sizeof(int), stream);

    int bblocks = (2 * E + 4095) / 4096;
    bucket_k<<<bblocks, 256, 0, stream>>>(pos, neg, pcnt, ebuf, E, n, nb);
    bscan_k <<<1, 512, 0, stream>>>(pcnt, bbase, nb);
    scatter_k<<<nb, 256, 0, stream>>>(ebuf, pcnt, bbase, cur, col, n);

    int n4 = n * 16;                         // h4 elements of x
    cvt_k  <<<(n4 + 255) / 256, 256, 0, stream>>>((const float4*)x, (h4*)xh, n4);

    int lblocks = 2048;   // 8 blocks/CU resident; grid-stride over nodes
    layer1_pull<<<lblocks, 256, 0, stream>>>((const h4*)xh, cur, col,
                                             W1p, b1p, W1n, b1n, zh, n);
    layer2_pull<<<lblocks, 256, 0, stream>>>((const h4*)zh, cur, col,
                                             W2p, b2p, W2n, b2n,
                                             (float*)d_out, n);
}